// Round 10
// baseline (3603.179 us; speedup 1.0000x reference)
//
#include <hip/hip_runtime.h>

// Problem constants (fixed by the reference)
#define NU 100000
#define NV 50000
#define KSUP 5
#define ESUP 400000
#define NEDGE (KSUP * ESUP)   // 2,000,000
#define NE 500000
#define DIN 512
#define DGCN 500
#define FSUP 100     // DGCN / KSUP
#define DSIDE 128
#define HSIDE 64
#define DENC 128
#define NBAS 3
#define NCLS 5

#define TMPW 640     // padded tmp width: 5 supports x 128 (256B-aligned slices)
#define XW 576       // X width: 500 gcn + 64 side + 12 pad (K = 9*64)

// two-level scatter geometry
#define RU 98        // ceil(NU/1024) node ranges (U)
#define RV 49        // ceil(NV/1024) node ranges (V)
#define NBU (KSUP * RU)   // 490 U buckets
#define NBV (KSUP * RV)   // 245 V buckets
#define CAPU 5120    // mean 4096, +16 sigma
#define CAPV 10240   // mean 8192, +22 sigma

__device__ __forceinline__ ushort f2bf(float x) {
    union { float f; unsigned u; } c; c.f = x;
    unsigned r = (c.u + 0x7FFFu + ((c.u >> 16) & 1u)) >> 16;   // RNE
    return (ushort)r;
}
__device__ __forceinline__ float bf2f(ushort h) {
    union { unsigned u; float f; } c; c.u = ((unsigned)h) << 16;
    return c.f;
}
// unpack a u32 holding two bf16 (lo = even col, hi = odd col)
__device__ __forceinline__ float lof(uint g) { return __uint_as_float(g << 16); }
__device__ __forceinline__ float hif(uint g) { return __uint_as_float(g & 0xffff0000u); }

typedef __attribute__((ext_vector_type(4))) float f32x4;
typedef __attribute__((ext_vector_type(8))) short bf16x8;
typedef __attribute__((address_space(3))) void lds_void;
typedef const __attribute__((address_space(1))) void glob_void;
typedef unsigned long long ull;

// ---------------------------------------------------------------------------
// bf16 MFMA GEMM: C[M,N] = A[M,K](bf16,K-major) @ BT[N,K](bf16,K-major)^T
// 128x128 tile, BK=64, 4 waves (2x2). LDS XOR-swizzled via pre-swizzled
// global source (rule #21). STORE_BF16: 1 -> C ushort, 0 -> C float.
template<int STORE_BF16>
__global__ __launch_bounds__(256) void gemm_bf16_k(
    const ushort* __restrict__ A, const ushort* __restrict__ BT,
    void* __restrict__ Cout, int M, int N, int K, int ldc)
{
    __shared__ ushort As[128 * 64];
    __shared__ ushort Bs[128 * 64];
    const int t = threadIdx.x;
    const int lane = t & 63;
    const int w = t >> 6;
    const int wr = w >> 1, wc = w & 1;
    const int rowBase = blockIdx.x * 128;
    const int colBase = blockIdx.y * 128;

    f32x4 acc[4][4] = {};

    for (int k0 = 0; k0 < K; k0 += 64) {
        #pragma unroll
        for (int i = 0; i < 4; ++i) {
            int chi = i * 256 + t;
            int r = chi >> 3;
            int c = (((chi >> 3) & 7) ^ (chi & 7)) * 8;
            int ga = rowBase + r; if (ga > M - 1) ga = M - 1;
            __builtin_amdgcn_global_load_lds(
                (glob_void*)(A + (size_t)ga * K + k0 + c),
                (lds_void*)(As + (size_t)chi * 8), 16, 0, 0);
            int gb = colBase + r; if (gb > N - 1) gb = N - 1;
            __builtin_amdgcn_global_load_lds(
                (glob_void*)(BT + (size_t)gb * K + k0 + c),
                (lds_void*)(Bs + (size_t)chi * 8), 16, 0, 0);
        }
        __syncthreads();

        #pragma unroll
        for (int kk = 0; kk < 2; ++kk) {
            bf16x8 af[4], bfr[4];
            const int cb2 = (kk * 32 + (lane >> 4) * 8) * 2;
            #pragma unroll
            for (int mi = 0; mi < 4; ++mi) {
                int r = wr * 64 + mi * 16 + (lane & 15);
                int off = (r * 128 + cb2) ^ ((r & 7) << 4);
                af[mi] = *(const bf16x8*)((const char*)As + off);
            }
            #pragma unroll
            for (int nj = 0; nj < 4; ++nj) {
                int r = wc * 64 + nj * 16 + (lane & 15);
                int off = (r * 128 + cb2) ^ ((r & 7) << 4);
                bfr[nj] = *(const bf16x8*)((const char*)Bs + off);
            }
            #pragma unroll
            for (int mi = 0; mi < 4; ++mi)
                #pragma unroll
                for (int nj = 0; nj < 4; ++nj)
                    acc[mi][nj] = __builtin_amdgcn_mfma_f32_16x16x32_bf16(
                        af[mi], bfr[nj], acc[mi][nj], 0, 0, 0);
        }
        __syncthreads();
    }

    #pragma unroll
    for (int mi = 0; mi < 4; ++mi) {
        #pragma unroll
        for (int q = 0; q < 4; ++q) {
            int gr = rowBase + wr * 64 + mi * 16 + (lane >> 4) * 4 + q;
            if (gr >= M) continue;
            #pragma unroll
            for (int nj = 0; nj < 4; ++nj) {
                int gc = colBase + wc * 64 + nj * 16 + (lane & 15);
                float v = acc[mi][nj][q];
                if (STORE_BF16)
                    ((ushort*)Cout)[(size_t)gr * ldc + gc] = f2bf(v);
                else
                    ((float*)Cout)[(size_t)gr * ldc + gc] = v;
            }
        }
    }
}

// ---------------------------------------------------------------------------
// side dense (fp32 compute): writes bf16 relu(A@B+bias) into X cols [500,564)
#define BM 64
#define BN 64
#define BK 16
__global__ __launch_bounds__(256) void gemm_side_k(
    const float* __restrict__ A, const float* __restrict__ B,
    const float* __restrict__ bias, ushort* __restrict__ X,
    int M, int K)
{
    __shared__ float As[BK][BM + 4];
    __shared__ float Bs[BK][BN + 4];
    const int t = threadIdx.x;
    const int rowBase = blockIdx.x * BM;
    const int ty = t >> 4, tx = t & 15;
    float acc[4][4] = {};

    for (int k0 = 0; k0 < K; k0 += BK) {
        #pragma unroll
        for (int p = 0; p < 4; ++p) {
            int r = p * 16 + (t >> 4), kk = t & 15;
            int gr = rowBase + r, gk = k0 + kk;
            As[kk][r] = (gr < M && gk < K) ? A[(size_t)gr * K + gk] : 0.f;
        }
        #pragma unroll
        for (int p = 0; p < 4; ++p) {
            int kk = p * 4 + (t >> 6), j = t & 63;
            int gk = k0 + kk;
            Bs[kk][j] = (j < HSIDE && gk < K) ? B[(size_t)gk * HSIDE + j] : 0.f;
        }
        __syncthreads();
        #pragma unroll
        for (int kk = 0; kk < BK; ++kk) {
            float4 a4 = *reinterpret_cast<const float4*>(&As[kk][ty * 4]);
            float4 b4 = *reinterpret_cast<const float4*>(&Bs[kk][tx * 4]);
            float aa[4] = {a4.x, a4.y, a4.z, a4.w};
            float bb[4] = {b4.x, b4.y, b4.z, b4.w};
            #pragma unroll
            for (int i = 0; i < 4; ++i)
                #pragma unroll
                for (int j = 0; j < 4; ++j)
                    acc[i][j] = fmaf(aa[i], bb[j], acc[i][j]);
        }
        __syncthreads();
    }
    #pragma unroll
    for (int i = 0; i < 4; ++i) {
        int gr = rowBase + ty * 4 + i;
        if (gr >= M) continue;
        #pragma unroll
        for (int j = 0; j < 4; ++j) {
            int gc = tx * 4 + j;
            if (gc < HSIDE)
                X[(size_t)gr * XW + 500 + gc] = f2bf(fmaxf(acc[i][j] + bias[gc], 0.f));
        }
    }
}

// ---------------------------------------------------------------------------
// conversions
__global__ __launch_bounds__(256) void cvt_k(const float* __restrict__ in,
                                             ushort* __restrict__ out, long n) {
    long i = ((long)blockIdx.x * 256 + threadIdx.x) * 4;
    if (i >= n) return;
    float4 v = *(const float4*)(in + i);
    ushort4 o;
    o.x = f2bf(v.x); o.y = f2bf(v.y); o.z = f2bf(v.z); o.w = f2bf(v.w);
    *(ushort4*)(out + i) = o;
}

// fused u/v input conversion
__global__ __launch_bounds__(256) void cvt_in_k(
    const float* __restrict__ u_in, const float* __restrict__ v_in,
    ushort* __restrict__ u_bf, ushort* __restrict__ v_bf)
{
    long i = ((long)blockIdx.x * 256 + threadIdx.x) * 4;
    const long nu = (long)NU * 512;
    const float* src; ushort* dst;
    if (i < nu) { src = u_in; dst = u_bf; }
    else {
        i -= nu;
        if (i >= (long)NV * 512) return;
        src = v_in; dst = v_bf;
    }
    float4 v = *(const float4*)(src + i);
    ushort4 o;
    o.x = f2bf(v.x); o.y = f2bf(v.y); o.z = f2bf(v.z); o.w = f2bf(v.w);
    *(ushort4*)(dst + i) = o;
}

// WencT2[n'][d], n' in [0,640): k=n'>>7, f=n'&127; val = f<100 ? W_enc[k][d][f] : 0
__global__ __launch_bounds__(256) void cvt_wencT2_k(const float* __restrict__ W,
                                                    ushort* __restrict__ out) {
    int idx = blockIdx.x * 256 + threadIdx.x;   // 640*512
    int np = idx >> 9, d = idx & 511;
    int k = np >> 7, f = np & 127;
    float v = (f < FSUP) ? W[((size_t)k * DIN + d) * FSUP + f] : 0.f;
    out[idx] = f2bf(v);
}

// W2fT[j][c] = bf16(W2[c][j]) for c<564, 0 for pad; both U and I via blockIdx.y
__global__ __launch_bounds__(256) void cvt_w2fT2_k(
    const float* __restrict__ Wu2, const float* __restrict__ Wi2,
    ushort* __restrict__ outU, ushort* __restrict__ outI)
{
    int idx = blockIdx.x * 256 + threadIdx.x;   // 128*576
    if (idx >= DENC * XW) return;
    const float* W = blockIdx.y ? Wi2 : Wu2;
    ushort* out = blockIdx.y ? outI : outU;
    int j = idx / XW, c = idx - j * XW;
    float v = (c < DGCN + HSIDE) ? W[(size_t)c * DENC + j] : 0.f;
    out[idx] = f2bf(v);
}

// ---------------------------------------------------------------------------
// Level-1: fused histogram + coarse binning. Bucket entry (8B):
//  U: word0 = (r_local<<16)|c, word1 = val bits   (bucket = k*RU + r>>10)
//  V: word0 = (c_local<<17)|r, word1 = val bits   (bucket = k*RV + c>>10)
// Bucket appends are sequential per bucket -> full-line writebacks.
__global__ __launch_bounds__(256) void binhist_k(
    const int* __restrict__ su, const int* __restrict__ si,
    const float* __restrict__ sv,
    int* __restrict__ histU, int* __restrict__ histV,
    int* __restrict__ bCntU, int* __restrict__ bCntV,
    ull* __restrict__ bktU, ull* __restrict__ bktV)
{
    int e = blockIdx.x * 256 + threadIdx.x;
    if (e >= NEDGE) return;
    int k = e / ESUP;
    int r = su[e], c = si[e];
    ull vb = (ull)(unsigned)__float_as_int(sv[e]) << 32;
    atomicAdd(&histU[k * NU + r], 1);
    atomicAdd(&histV[k * NV + c], 1);
    int bu = k * RU + (r >> 10);
    int pu = atomicAdd(&bCntU[bu], 1);
    if (pu < CAPU)
        __builtin_nontemporal_store(vb | (uint)(((r & 1023) << 16) | c),
                                    &bktU[(size_t)bu * CAPU + pu]);
    int bv = k * RV + (c >> 10);
    int pv = atomicAdd(&bCntV[bv], 1);
    if (pv < CAPV)
        __builtin_nontemporal_store(vb | (uint)(((c & 1023) << 17) | r),
                                    &bktV[(size_t)bv * CAPV + pv]);
}

__global__ __launch_bounds__(256) void scan_reduce_k(const int* __restrict__ in,
                                                     int* __restrict__ bs, int n) {
    __shared__ int sm[256];
    int base = blockIdx.x * 2048 + threadIdx.x * 8;
    int s = 0;
    #pragma unroll
    for (int i = 0; i < 8; ++i) { int idx = base + i; if (idx < n) s += in[idx]; }
    sm[threadIdx.x] = s; __syncthreads();
    for (int off = 128; off; off >>= 1) {
        if (threadIdx.x < off) sm[threadIdx.x] += sm[threadIdx.x + off];
        __syncthreads();
    }
    if (threadIdx.x == 0) bs[blockIdx.x] = sm[0];
}

__global__ __launch_bounds__(256) void scan_bs_k(int* __restrict__ bs, int nb) {
    __shared__ int sm[256];
    int t = threadIdx.x;
    int v = (t < nb) ? bs[t] : 0;
    sm[t] = v; __syncthreads();
    for (int off = 1; off < 256; off <<= 1) {
        int add = (t >= off) ? sm[t - off] : 0;
        __syncthreads();
        sm[t] += add;
        __syncthreads();
    }
    if (t < nb) bs[t] = sm[t] - v;   // exclusive
}

__global__ __launch_bounds__(256) void scan_write_k(const int* __restrict__ in,
                                                    const int* __restrict__ bs,
                                                    int* __restrict__ out,
                                                    int* __restrict__ pos, int n) {
    __shared__ int sm[256];
    int t = threadIdx.x;
    int base = blockIdx.x * 2048 + t * 8;
    int loc[8]; int s = 0;
    #pragma unroll
    for (int i = 0; i < 8; ++i) {
        int idx = base + i;
        loc[i] = (idx < n) ? in[idx] : 0;
        s += loc[i];
    }
    sm[t] = s; __syncthreads();
    int sv = s;
    for (int off = 1; off < 256; off <<= 1) {
        int add = (t >= off) ? sm[t - off] : 0;
        __syncthreads();
        sm[t] += add;
        __syncthreads();
    }
    int thOff = bs[blockIdx.x] + sm[t] - sv;
    int run = 0;
    #pragma unroll
    for (int i = 0; i < 8; ++i) {
        int idx = base + i;
        if (idx < n) { int v = thOff + run; out[idx] = v; pos[idx] = v; }
        run += loc[i];
    }
    if (blockIdx.x == 0 && t == 0) out[n] = NEDGE;   // sentinel (padded buffer)
}

// Level-2 scatter: one block per bucket; destination window is the ~32-64KB
// CSR slice for this bucket's 1024 nodes -> L2-resident, full-line writebacks.
__global__ __launch_bounds__(256) void scat2_k(
    const int* __restrict__ bCntU, const int* __restrict__ bCntV,
    const ull* __restrict__ bktU, const ull* __restrict__ bktV,
    int* __restrict__ posU, int* __restrict__ posV,
    ull* __restrict__ eU, ull* __restrict__ eV)
{
    int b = blockIdx.x;
    if (b < NBU) {
        int k = b / RU, baseR = (b % RU) << 10;
        int cnt = bCntU[b]; if (cnt > CAPU) cnt = CAPU;
        const ull* src = bktU + (size_t)b * CAPU;
        for (int i = threadIdx.x; i < cnt; i += 256) {
            ull en = src[i];
            uint w0 = (uint)en;
            int c = w0 & 0xFFFF;
            int r = baseR + (int)(w0 >> 16);
            int p = atomicAdd(&posU[k * NU + r], 1);
            __builtin_nontemporal_store((en & 0xFFFFFFFF00000000ull) |
                                        (uint)(c * (TMPW * 2)), &eU[p]);
        }
    } else {
        b -= NBU;
        int k = b / RV, baseC = (b % RV) << 10;
        int cnt = bCntV[b]; if (cnt > CAPV) cnt = CAPV;
        const ull* src = bktV + (size_t)b * CAPV;
        for (int i = threadIdx.x; i < cnt; i += 256) {
            ull en = src[i];
            uint w0 = (uint)en;
            int r = w0 & 0x1FFFF;
            int c = baseC + (int)(w0 >> 17);
            int p = atomicAdd(&posV[k * NV + c], 1);
            __builtin_nontemporal_store((en & 0xFFFFFFFF00000000ull) |
                                        (uint)(r * (TMPW * 2)), &eV[p]);
        }
    }
}

// ---------------------------------------------------------------------------
// Merged-support CSR aggregation: ONE wave per node, all supports [K0,K0+NK)
// in one interleaved latency chain (rowPtrs -> edges -> gathers -> fma).
template<int K0, int NK, int B, int NNODE>
__device__ __forceinline__ void agg_do(
    const int* __restrict__ rowPtr, const int2* __restrict__ eArr,
    const char* __restrict__ tSrc, int n, uint lane4,
    float* __restrict__ a0, float* __restrict__ a1)
{
    int s[NK], d[NK];
    #pragma unroll
    for (int kk = 0; kk < NK; ++kk) {
        int g = (K0 + kk) * NNODE + n;
        int ss = rowPtr[g];
        int ee = rowPtr[g + 1];     // sentinel covers the last segment
        s[kk] = ss; d[kk] = ee - ss;
    }
    int2 ed[NK][B]; uint gw[NK][B];
    #pragma unroll
    for (int kk = 0; kk < NK; ++kk)
        #pragma unroll
        for (int i = 0; i < B; ++i) {
            int idx = (i < d[kk]) ? i : 0;
            int2 t = eArr[s[kk] + idx];
            if (i >= d[kk]) t.x = 0;
            ed[kk][i] = t;
        }
    #pragma unroll
    for (int kk = 0; kk < NK; ++kk)
        #pragma unroll
        for (int i = 0; i < B; ++i)
            gw[kk][i] = *(const uint*)(tSrc + ((uint)ed[kk][i].x + lane4 + ((uint)(K0 + kk) << 8)));
    #pragma unroll
    for (int kk = 0; kk < NK; ++kk) {
        float x0 = 0.f, x1 = 0.f;
        #pragma unroll
        for (int i = 0; i < B; ++i)
            if (i < d[kk]) {
                float v = __int_as_float(ed[kk][i].y);
                x0 = fmaf(v, lof(gw[kk][i]), x0);
                x1 = fmaf(v, hif(gw[kk][i]), x1);
            }
        a0[K0 + kk] = x0; a1[K0 + kk] = x1;
    }
    #pragma unroll
    for (int kk = 0; kk < NK; ++kk) {
        if (d[kk] > B) {            // wave-uniform branch
            int2 e1[B]; uint g1[B];
            #pragma unroll
            for (int i = 0; i < B; ++i) {
                int idx = (B + i < d[kk]) ? B + i : B;
                int2 t = eArr[s[kk] + idx];
                if (B + i >= d[kk]) t.x = 0;
                e1[i] = t;
            }
            #pragma unroll
            for (int i = 0; i < B; ++i)
                g1[i] = *(const uint*)(tSrc + ((uint)e1[i].x + lane4 + ((uint)(K0 + kk) << 8)));
            #pragma unroll
            for (int i = 0; i < B; ++i)
                if (B + i < d[kk]) {
                    float v = __int_as_float(e1[i].y);
                    a0[K0 + kk] = fmaf(v, lof(g1[i]), a0[K0 + kk]);
                    a1[K0 + kk] = fmaf(v, hif(g1[i]), a1[K0 + kk]);
                }
            for (int p = 2 * B; p < d[kk]; ++p) {
                int2 t = eArr[s[kk] + p];
                uint g = *(const uint*)(tSrc + ((uint)t.x + lane4 + ((uint)(K0 + kk) << 8)));
                float v = __int_as_float(t.y);
                a0[K0 + kk] = fmaf(v, lof(g), a0[K0 + kk]);
                a1[K0 + kk] = fmaf(v, hif(g), a1[K0 + kk]);
            }
        }
    }
}

__global__ __launch_bounds__(256) void agg_csr_k(
    const int* __restrict__ rowPtrU, const int2* __restrict__ eU,
    const int* __restrict__ rowPtrV, const int2* __restrict__ eV,
    const ushort* __restrict__ tmpU, const ushort* __restrict__ tmpV,
    ushort* __restrict__ Xu, ushort* __restrict__ Xv)
{
    const int lane = threadIdx.x & 63;
    const int wv = blockIdx.x * 4 + (threadIdx.x >> 6);   // node id (U then V)
    const uint lane4 = (uint)(((lane < 50) ? lane : 49) << 2);

    float a0[KSUP], a1[KSUP];
    ushort* Xrow;
    if (wv < NU) {
        agg_do<0, KSUP, 4, NU>(rowPtrU, eU, (const char*)tmpV, wv, lane4, a0, a1);
        Xrow = Xu + (size_t)wv * XW;
    } else {
        int n = wv - NU;
        agg_do<0, 3, 8, NV>(rowPtrV, eV, (const char*)tmpU, n, lane4, a0, a1);
        agg_do<3, 2, 8, NV>(rowPtrV, eV, (const char*)tmpU, n, lane4, a0, a1);
        Xrow = Xv + (size_t)n * XW;
    }
    #pragma unroll
    for (int k = 0; k < KSUP; ++k) {
        uint payload = (uint)f2bf(fmaxf(a0[k], 0.f)) |
                       ((uint)f2bf(fmaxf(a1[k], 0.f)) << 16);
        if (lane < 50)
            __builtin_nontemporal_store(payload, (uint*)(Xrow + k * FSUP) + lane);
    }
    if (lane < 6)
        __builtin_nontemporal_store(0u, (uint*)(Xrow + 564) + lane);
}

// ---------------------------------------------------------------------------
// final decoder: basis[b] = dot(embU[u], Vb[v][b]); out = basis @ cls
__global__ __launch_bounds__(256) void dec_k(
    const int* __restrict__ ue, const int* __restrict__ ie,
    const ushort* __restrict__ embU, const ushort* __restrict__ Vb,
    const float* __restrict__ cls, float* __restrict__ out, int nE)
{
    int e = blockIdx.x * 8 + (threadIdx.x >> 5);
    if (e >= nE) return;
    int lane = threadIdx.x & 31;
    int u = ue[e], v = ie[e];
    const uint* pu = (const uint*)(embU + (size_t)u * DENC);        // 64 u32
    const uint* pv = (const uint*)(Vb + (size_t)v * (NBAS * DENC)); // 192 u32
    uint u0 = pu[lane], u1 = pu[lane + 32];
    uint b0[NBAS], b1[NBAS];
    #pragma unroll
    for (int b = 0; b < NBAS; ++b) {
        b0[b] = pv[b * 64 + lane];
        b1[b] = pv[b * 64 + 32 + lane];
    }
    float u0l = lof(u0), u0h = hif(u0), u1l = lof(u1), u1h = hif(u1);
    float s[NBAS];
    #pragma unroll
    for (int b = 0; b < NBAS; ++b) {
        float t = lof(b0[b]) * u0l;
        t = fmaf(hif(b0[b]), u0h, t);
        t = fmaf(lof(b1[b]), u1l, t);
        s[b] = fmaf(hif(b1[b]), u1h, t);
    }
    #pragma unroll
    for (int off = 16; off; off >>= 1)
        #pragma unroll
        for (int b = 0; b < NBAS; ++b) s[b] += __shfl_xor(s[b], off, 32);
    if (lane < NCLS) {
        float o = 0.f;
        #pragma unroll
        for (int b = 0; b < NBAS; ++b) o += s[b] * cls[b * NCLS + lane];
        out[(size_t)e * NCLS + lane] = o;
    }
}

// ---------------------------------------------------------------------------
extern "C" void kernel_launch(void* const* d_in, const int* in_sizes, int n_in,
                              void* d_out, int out_size, void* d_ws, size_t ws_size,
                              hipStream_t stream) {
    const int*   sup_u  = (const int*)  d_in[0];
    const int*   sup_i  = (const int*)  d_in[1];
    const float* sup_v  = (const float*)d_in[2];
    const float* u_in   = (const float*)d_in[3];
    const float* v_in   = (const float*)d_in[4];
    const float* u_side = (const float*)d_in[5];
    const float* v_side = (const float*)d_in[6];
    const int*   ue     = (const int*)  d_in[7];
    const int*   ie     = (const int*)  d_in[8];
    const float* W_enc  = (const float*)d_in[9];
    const float* Wu1    = (const float*)d_in[10];
    const float* bu1    = (const float*)d_in[11];
    const float* Wi1    = (const float*)d_in[12];
    const float* bi1    = (const float*)d_in[13];
    const float* Wu2    = (const float*)d_in[14];
    const float* Wi2    = (const float*)d_in[15];
    const float* dec_W  = (const float*)d_in[16];
    const float* deccls = (const float*)d_in[17];

    char* ws = (char*)d_ws;
    // timeline-overlaid workspace (max ~414M):
    // @0: u_bf [NU][512] (102.4M) -> Xu [NU][576] (115.2M)
    // @102.4M: v_bf [NV][512] (51.2M); Xv @115.2M [NV][576] (57.6M) ends 172.8M
    ushort* u_bf   = (ushort*)(ws);
    ushort* v_bf   = (ushort*)(ws + 102400000LL);
    ushort* Xu     = (ushort*)(ws);
    ushort* Xv     = (ushort*)(ws + 115200000LL);
    // CSR @176M (dead after agg); rowPtr regions padded for the +1 sentinel.
    int*    histU  = (int*)(ws + 176000000LL);          // [5][NU] 2M
    int*    histV  = (int*)(ws + 178000000LL);          // [5][NV] 1M
    int*    rowPtrU= (int*)(ws + 179000000LL);          // 2M + 4 sentinel
    int*    rowPtrV= (int*)(ws + 181200000LL);          // 1M + 4 sentinel
    int*    posU   = (int*)(ws + 182400000LL);          // 2M
    int*    posV   = (int*)(ws + 184600000LL);          // 1M
    int*    bsums  = (int*)(ws + 185800000LL);          // 4KB
    int*    bCntU  = (int*)(ws + 185810000LL);          // 490*4
    int*    bCntV  = (int*)(ws + 185815000LL);          // 245*4
    ull*    eU     = (ull*)(ws + 186000000LL);          // [2M] 16M
    ull*    eV     = (ull*)(ws + 202000000LL);          // [2M] 16M ends 218M
    // tmp @220M (dead after agg): tmpU [NU][640] 128M, tmpV [NV][640] 64M
    ushort* tmpU   = (ushort*)(ws + 220000000LL);
    ushort* tmpV   = (ushort*)(ws + 348000000LL);       // ends 412M
    // L1 buckets: overlay on tmp region (dead before encoder GEMMs write tmp)
    ull*    bktU   = (ull*)(ws + 220000000LL);          // 490*5120*8  = 20.1M
    ull*    bktV   = (ull*)(ws + 241000000LL);          // 245*10240*8 = 20.1M ends 261.1M
    // post-agg overlays:
    ushort* embUbf = (ushort*)(ws + 176000000LL);       // [NU][128] 25.6M (over CSR)
    ushort* embVbf = (ushort*)(ws + 202000000LL);       // [NV][128] 12.8M (over eV)
    ushort* Vb     = (ushort*)(ws + 220000000LL);       // [NV][384] 38.4M (over tmp)
    // weights @412M:
    ushort* WencT2 = (ushort*)(ws + 412000000LL);       // [640][512] 0.66M
    ushort* W2ufT  = (ushort*)(ws + 413000000LL);       // [128][576] 0.15M
    ushort* W2ifT  = (ushort*)(ws + 413200000LL);       // [128][576] 0.15M
    ushort* decbf  = (ushort*)(ws + 413400000LL);       // [384][128] 0.10M

    dim3 blk(256);
    const int gu128 = (NU + 127) / 128;   // 782
    const int gv128 = (NV + 127) / 128;   // 391
    const int gu64  = (NU + 63) / 64;     // 1563
    const int gv64  = (NV + 63) / 64;     // 782
    const int gE    = (NEDGE + 255) / 256;

    // ---- phase 1: bf16 conversions + CSR build (two-level scatter) ----
    cvt_in_k<<<dim3((NU + NV) * 512 / 4 / 256), blk, 0, stream>>>(u_in, v_in, u_bf, v_bf);
    cvt_wencT2_k<<<dim3(TMPW * 512 / 256), blk, 0, stream>>>(W_enc, WencT2);
    cvt_w2fT2_k<<<dim3((DENC * XW + 255) / 256, 2), blk, 0, stream>>>(Wu2, Wi2, W2ufT, W2ifT);
    cvt_k<<<dim3((NBAS * DENC * DENC / 4 + 255) / 256), blk, 0, stream>>>(
        dec_W, decbf, (long)NBAS * DENC * DENC);

    hipMemsetAsync(histU, 0, 3000000LL, stream);        // histU + histV
    hipMemsetAsync(bCntU, 0, 8192, stream);             // bCntU + bCntV
    binhist_k<<<dim3(gE), blk, 0, stream>>>(sup_u, sup_i, sup_v,
                                            histU, histV, bCntU, bCntV, bktU, bktV);
    scan_reduce_k<<<dim3(245), blk, 0, stream>>>(histU, bsums, KSUP * NU);
    scan_bs_k<<<dim3(1), blk, 0, stream>>>(bsums, 245);
    scan_write_k<<<dim3(245), blk, 0, stream>>>(histU, bsums, rowPtrU, posU, KSUP * NU);
    scan_reduce_k<<<dim3(123), blk, 0, stream>>>(histV, bsums, KSUP * NV);
    scan_bs_k<<<dim3(1), blk, 0, stream>>>(bsums, 123);
    scan_write_k<<<dim3(123), blk, 0, stream>>>(histV, bsums, rowPtrV, posV, KSUP * NV);
    scat2_k<<<dim3(NBU + NBV), blk, 0, stream>>>(bCntU, bCntV, bktU, bktV,
                                                 posU, posV, eU, eV);

    // ---- phase 2: encoder GEMMs into padded tmp (N=640, 256B slices) ----
    gemm_bf16_k<1><<<dim3(gu128, TMPW / 128), blk, 0, stream>>>(
        u_bf, WencT2, tmpU, NU, TMPW, 512, TMPW);
    gemm_bf16_k<1><<<dim3(gv128, TMPW / 128), blk, 0, stream>>>(
        v_bf, WencT2, tmpV, NV, TMPW, 512, TMPW);

    // ---- phase 3: merged CSR aggregation (1 wave/node, 5 supports) ----
    agg_csr_k<<<dim3((NU + NV) / 4), blk, 0, stream>>>(
        rowPtrU, (const int2*)eU, rowPtrV, (const int2*)eV, tmpU, tmpV, Xu, Xv);

    // ---- phase 4: side dense -> X cols 500..563 (bf16) ----
    gemm_side_k<<<dim3(gu64), blk, 0, stream>>>(u_side, Wu1, bu1, Xu, NU, DSIDE);
    gemm_side_k<<<dim3(gv64), blk, 0, stream>>>(v_side, Wi1, bi1, Xv, NV, DSIDE);

    // ---- phase 5: dense2 = X @ W2fT (K=576) -> emb bf16 ----
    gemm_bf16_k<1><<<dim3(gu128, 1), blk, 0, stream>>>(Xu, W2ufT, embUbf, NU, 128, XW, 128);
    gemm_bf16_k<1><<<dim3(gv128, 1), blk, 0, stream>>>(Xv, W2ifT, embVbf, NV, 128, XW, 128);

    // ---- phase 6: decoder precompute on V side: Vb = embV @ decbf^T ----
    gemm_bf16_k<1><<<dim3(gv128, 3), blk, 0, stream>>>(embVbf, decbf, Vb, NV, 384, 128, 384);

    // ---- phase 7: final decoder over edges ----
    dec_k<<<dim3(NE / 8), blk, 0, stream>>>(ue, ie, embUbf, Vb, deccls, (float*)d_out, NE);
}

// Round 11
// 1233.696 us; speedup vs baseline: 2.9206x; 2.9206x over previous
//
#include <hip/hip_runtime.h>

// Problem constants (fixed by the reference)
#define NU 100000
#define NV 50000
#define KSUP 5
#define ESUP 400000
#define NEDGE (KSUP * ESUP)   // 2,000,000
#define NE 500000
#define DIN 512
#define DGCN 500
#define FSUP 100     // DGCN / KSUP
#define DSIDE 128
#define HSIDE 64
#define DENC 128
#define NBAS 3
#define NCLS 5

#define TMPW 640     // padded tmp width: 5 supports x 128 (256B-aligned slices)
#define XW 576       // X width: 500 gcn + 64 side + 12 pad (K = 9*64)

// two-level scatter geometry
#define RU 98        // ceil(NU/1024) node ranges (U)
#define RV 49        // ceil(NV/1024) node ranges (V)
#define NBU (KSUP * RU)   // 490 U buckets
#define NBV (KSUP * RV)   // 245 V buckets
#define NBT (NBU + NBV)   // 735
#define CAPU 5120    // mean 4096, +16 sigma
#define CAPV 10240   // mean 8192, +22 sigma
#define CHUNK 8192   // edges per block in binhist

__device__ __forceinline__ ushort f2bf(float x) {
    union { float f; unsigned u; } c; c.f = x;
    unsigned r = (c.u + 0x7FFFu + ((c.u >> 16) & 1u)) >> 16;   // RNE
    return (ushort)r;
}
__device__ __forceinline__ float bf2f(ushort h) {
    union { unsigned u; float f; } c; c.u = ((unsigned)h) << 16;
    return c.f;
}
// unpack a u32 holding two bf16 (lo = even col, hi = odd col)
__device__ __forceinline__ float lof(uint g) { return __uint_as_float(g << 16); }
__device__ __forceinline__ float hif(uint g) { return __uint_as_float(g & 0xffff0000u); }

typedef __attribute__((ext_vector_type(4))) float f32x4;
typedef __attribute__((ext_vector_type(8))) short bf16x8;
typedef __attribute__((address_space(3))) void lds_void;
typedef const __attribute__((address_space(1))) void glob_void;
typedef unsigned long long ull;

// ---------------------------------------------------------------------------
// bf16 MFMA GEMM: C[M,N] = A[M,K](bf16,K-major) @ BT[N,K](bf16,K-major)^T
// 128x128 tile, BK=64, 4 waves (2x2). LDS XOR-swizzled via pre-swizzled
// global source (rule #21). STORE_BF16: 1 -> C ushort, 0 -> C float.
template<int STORE_BF16>
__global__ __launch_bounds__(256) void gemm_bf16_k(
    const ushort* __restrict__ A, const ushort* __restrict__ BT,
    void* __restrict__ Cout, int M, int N, int K, int ldc)
{
    __shared__ ushort As[128 * 64];
    __shared__ ushort Bs[128 * 64];
    const int t = threadIdx.x;
    const int lane = t & 63;
    const int w = t >> 6;
    const int wr = w >> 1, wc = w & 1;
    const int rowBase = blockIdx.x * 128;
    const int colBase = blockIdx.y * 128;

    f32x4 acc[4][4] = {};

    for (int k0 = 0; k0 < K; k0 += 64) {
        #pragma unroll
        for (int i = 0; i < 4; ++i) {
            int chi = i * 256 + t;
            int r = chi >> 3;
            int c = (((chi >> 3) & 7) ^ (chi & 7)) * 8;
            int ga = rowBase + r; if (ga > M - 1) ga = M - 1;
            __builtin_amdgcn_global_load_lds(
                (glob_void*)(A + (size_t)ga * K + k0 + c),
                (lds_void*)(As + (size_t)chi * 8), 16, 0, 0);
            int gb = colBase + r; if (gb > N - 1) gb = N - 1;
            __builtin_amdgcn_global_load_lds(
                (glob_void*)(BT + (size_t)gb * K + k0 + c),
                (lds_void*)(Bs + (size_t)chi * 8), 16, 0, 0);
        }
        __syncthreads();

        #pragma unroll
        for (int kk = 0; kk < 2; ++kk) {
            bf16x8 af[4], bfr[4];
            const int cb2 = (kk * 32 + (lane >> 4) * 8) * 2;
            #pragma unroll
            for (int mi = 0; mi < 4; ++mi) {
                int r = wr * 64 + mi * 16 + (lane & 15);
                int off = (r * 128 + cb2) ^ ((r & 7) << 4);
                af[mi] = *(const bf16x8*)((const char*)As + off);
            }
            #pragma unroll
            for (int nj = 0; nj < 4; ++nj) {
                int r = wc * 64 + nj * 16 + (lane & 15);
                int off = (r * 128 + cb2) ^ ((r & 7) << 4);
                bfr[nj] = *(const bf16x8*)((const char*)Bs + off);
            }
            #pragma unroll
            for (int mi = 0; mi < 4; ++mi)
                #pragma unroll
                for (int nj = 0; nj < 4; ++nj)
                    acc[mi][nj] = __builtin_amdgcn_mfma_f32_16x16x32_bf16(
                        af[mi], bfr[nj], acc[mi][nj], 0, 0, 0);
        }
        __syncthreads();
    }

    #pragma unroll
    for (int mi = 0; mi < 4; ++mi) {
        #pragma unroll
        for (int q = 0; q < 4; ++q) {
            int gr = rowBase + wr * 64 + mi * 16 + (lane >> 4) * 4 + q;
            if (gr >= M) continue;
            #pragma unroll
            for (int nj = 0; nj < 4; ++nj) {
                int gc = colBase + wc * 64 + nj * 16 + (lane & 15);
                float v = acc[mi][nj][q];
                if (STORE_BF16)
                    ((ushort*)Cout)[(size_t)gr * ldc + gc] = f2bf(v);
                else
                    ((float*)Cout)[(size_t)gr * ldc + gc] = v;
            }
        }
    }
}

// ---------------------------------------------------------------------------
// side dense (fp32 compute): writes bf16 relu(A@B+bias) into X cols [500,564)
#define BM 64
#define BN 64
#define BK 16
__global__ __launch_bounds__(256) void gemm_side_k(
    const float* __restrict__ A, const float* __restrict__ B,
    const float* __restrict__ bias, ushort* __restrict__ X,
    int M, int K)
{
    __shared__ float As[BK][BM + 4];
    __shared__ float Bs[BK][BN + 4];
    const int t = threadIdx.x;
    const int rowBase = blockIdx.x * BM;
    const int ty = t >> 4, tx = t & 15;
    float acc[4][4] = {};

    for (int k0 = 0; k0 < K; k0 += BK) {
        #pragma unroll
        for (int p = 0; p < 4; ++p) {
            int r = p * 16 + (t >> 4), kk = t & 15;
            int gr = rowBase + r, gk = k0 + kk;
            As[kk][r] = (gr < M && gk < K) ? A[(size_t)gr * K + gk] : 0.f;
        }
        #pragma unroll
        for (int p = 0; p < 4; ++p) {
            int kk = p * 4 + (t >> 6), j = t & 63;
            int gk = k0 + kk;
            Bs[kk][j] = (j < HSIDE && gk < K) ? B[(size_t)gk * HSIDE + j] : 0.f;
        }
        __syncthreads();
        #pragma unroll
        for (int kk = 0; kk < BK; ++kk) {
            float4 a4 = *reinterpret_cast<const float4*>(&As[kk][ty * 4]);
            float4 b4 = *reinterpret_cast<const float4*>(&Bs[kk][tx * 4]);
            float aa[4] = {a4.x, a4.y, a4.z, a4.w};
            float bb[4] = {b4.x, b4.y, b4.z, b4.w};
            #pragma unroll
            for (int i = 0; i < 4; ++i)
                #pragma unroll
                for (int j = 0; j < 4; ++j)
                    acc[i][j] = fmaf(aa[i], bb[j], acc[i][j]);
        }
        __syncthreads();
    }
    #pragma unroll
    for (int i = 0; i < 4; ++i) {
        int gr = rowBase + ty * 4 + i;
        if (gr >= M) continue;
        #pragma unroll
        for (int j = 0; j < 4; ++j) {
            int gc = tx * 4 + j;
            if (gc < HSIDE)
                X[(size_t)gr * XW + 500 + gc] = f2bf(fmaxf(acc[i][j] + bias[gc], 0.f));
        }
    }
}

// ---------------------------------------------------------------------------
// conversions
__global__ __launch_bounds__(256) void cvt_k(const float* __restrict__ in,
                                             ushort* __restrict__ out, long n) {
    long i = ((long)blockIdx.x * 256 + threadIdx.x) * 4;
    if (i >= n) return;
    float4 v = *(const float4*)(in + i);
    ushort4 o;
    o.x = f2bf(v.x); o.y = f2bf(v.y); o.z = f2bf(v.z); o.w = f2bf(v.w);
    *(ushort4*)(out + i) = o;
}

// fused u/v input conversion
__global__ __launch_bounds__(256) void cvt_in_k(
    const float* __restrict__ u_in, const float* __restrict__ v_in,
    ushort* __restrict__ u_bf, ushort* __restrict__ v_bf)
{
    long i = ((long)blockIdx.x * 256 + threadIdx.x) * 4;
    const long nu = (long)NU * 512;
    const float* src; ushort* dst;
    if (i < nu) { src = u_in; dst = u_bf; }
    else {
        i -= nu;
        if (i >= (long)NV * 512) return;
        src = v_in; dst = v_bf;
    }
    float4 v = *(const float4*)(src + i);
    ushort4 o;
    o.x = f2bf(v.x); o.y = f2bf(v.y); o.z = f2bf(v.z); o.w = f2bf(v.w);
    *(ushort4*)(dst + i) = o;
}

// WencT2[n'][d], n' in [0,640): k=n'>>7, f=n'&127; val = f<100 ? W_enc[k][d][f] : 0
__global__ __launch_bounds__(256) void cvt_wencT2_k(const float* __restrict__ W,
                                                    ushort* __restrict__ out) {
    int idx = blockIdx.x * 256 + threadIdx.x;   // 640*512
    int np = idx >> 9, d = idx & 511;
    int k = np >> 7, f = np & 127;
    float v = (f < FSUP) ? W[((size_t)k * DIN + d) * FSUP + f] : 0.f;
    out[idx] = f2bf(v);
}

// W2fT[j][c] = bf16(W2[c][j]) for c<564, 0 for pad; both U and I via blockIdx.y
__global__ __launch_bounds__(256) void cvt_w2fT2_k(
    const float* __restrict__ Wu2, const float* __restrict__ Wi2,
    ushort* __restrict__ outU, ushort* __restrict__ outI)
{
    int idx = blockIdx.x * 256 + threadIdx.x;   // 128*576
    if (idx >= DENC * XW) return;
    const float* W = blockIdx.y ? Wi2 : Wu2;
    ushort* out = blockIdx.y ? outI : outU;
    int j = idx / XW, c = idx - j * XW;
    float v = (c < DGCN + HSIDE) ? W[(size_t)c * DENC + j] : 0.f;
    out[idx] = f2bf(v);
}

// ---------------------------------------------------------------------------
// Level-1 binning, contention-free: per-block LDS histogram -> ONE global
// atomicAdd per (block, bucket) to reserve a range -> LDS-cursor appends.
// Also does the rowPtr histograms (500k counters, uncontended).
// Bucket entry (8B): U: w0=(r_local<<16)|c; V: w0=(c_local<<17)|r; w1=val.
__global__ __launch_bounds__(256) void binhist_k(
    const int* __restrict__ su, const int* __restrict__ si,
    const float* __restrict__ sv,
    int* __restrict__ histU, int* __restrict__ histV,
    int* __restrict__ bCnt,              // [NBT] contiguous (U then V)
    ull* __restrict__ bktU, ull* __restrict__ bktV)
{
    __shared__ int lcnt[NBT];
    __shared__ int lbase[NBT];
    const int t = threadIdx.x;
    const int e0 = blockIdx.x * CHUNK;

    for (int i = t; i < NBT; i += 256) lcnt[i] = 0;
    __syncthreads();

    // pass A: LDS bucket histogram + global rowPtr histograms
    for (int i = t; i < CHUNK; i += 256) {
        int e = e0 + i;
        if (e >= NEDGE) break;
        int k = e / ESUP;
        int r = su[e], c = si[e];
        atomicAdd(&histU[k * NU + r], 1);
        atomicAdd(&histV[k * NV + c], 1);
        atomicAdd(&lcnt[k * RU + (r >> 10)], 1);
        atomicAdd(&lcnt[NBU + k * RV + (c >> 10)], 1);
    }
    __syncthreads();

    // reserve global ranges: one atomic per (block, bucket)
    for (int i = t; i < NBT; i += 256) {
        int n = lcnt[i];
        lbase[i] = n ? atomicAdd(&bCnt[i], n) : 0;
    }
    __syncthreads();
    for (int i = t; i < NBT; i += 256) lcnt[i] = 0;
    __syncthreads();

    // pass B: append via LDS cursors (normal stores -> lines merge in L2)
    for (int i = t; i < CHUNK; i += 256) {
        int e = e0 + i;
        if (e >= NEDGE) break;
        int k = e / ESUP;
        int r = su[e], c = si[e];
        ull vb = (ull)(unsigned)__float_as_int(sv[e]) << 32;
        int bu = k * RU + (r >> 10);
        int pu = lbase[bu] + atomicAdd(&lcnt[bu], 1);
        if (pu < CAPU)
            bktU[(size_t)bu * CAPU + pu] = vb | (uint)(((r & 1023) << 16) | c);
        int bv = NBU + k * RV + (c >> 10);
        int pv = lbase[bv] + atomicAdd(&lcnt[bv], 1);
        if (pv < CAPV)
            bktV[(size_t)(bv - NBU) * CAPV + pv] = vb | (uint)(((c & 1023) << 17) | r);
    }
}

__global__ __launch_bounds__(256) void scan_reduce_k(const int* __restrict__ in,
                                                     int* __restrict__ bs, int n) {
    __shared__ int sm[256];
    int base = blockIdx.x * 2048 + threadIdx.x * 8;
    int s = 0;
    #pragma unroll
    for (int i = 0; i < 8; ++i) { int idx = base + i; if (idx < n) s += in[idx]; }
    sm[threadIdx.x] = s; __syncthreads();
    for (int off = 128; off; off >>= 1) {
        if (threadIdx.x < off) sm[threadIdx.x] += sm[threadIdx.x + off];
        __syncthreads();
    }
    if (threadIdx.x == 0) bs[blockIdx.x] = sm[0];
}

__global__ __launch_bounds__(256) void scan_bs_k(int* __restrict__ bs, int nb) {
    __shared__ int sm[256];
    int t = threadIdx.x;
    int v = (t < nb) ? bs[t] : 0;
    sm[t] = v; __syncthreads();
    for (int off = 1; off < 256; off <<= 1) {
        int add = (t >= off) ? sm[t - off] : 0;
        __syncthreads();
        sm[t] += add;
        __syncthreads();
    }
    if (t < nb) bs[t] = sm[t] - v;   // exclusive
}

__global__ __launch_bounds__(256) void scan_write_k(const int* __restrict__ in,
                                                    const int* __restrict__ bs,
                                                    int* __restrict__ out,
                                                    int* __restrict__ pos, int n) {
    __shared__ int sm[256];
    int t = threadIdx.x;
    int base = blockIdx.x * 2048 + t * 8;
    int loc[8]; int s = 0;
    #pragma unroll
    for (int i = 0; i < 8; ++i) {
        int idx = base + i;
        loc[i] = (idx < n) ? in[idx] : 0;
        s += loc[i];
    }
    sm[t] = s; __syncthreads();
    int sv = s;
    for (int off = 1; off < 256; off <<= 1) {
        int add = (t >= off) ? sm[t - off] : 0;
        __syncthreads();
        sm[t] += add;
        __syncthreads();
    }
    int thOff = bs[blockIdx.x] + sm[t] - sv;
    int run = 0;
    #pragma unroll
    for (int i = 0; i < 8; ++i) {
        int idx = base + i;
        if (idx < n) { int v = thOff + run; out[idx] = v; pos[idx] = v; }
        run += loc[i];
    }
    if (blockIdx.x == 0 && t == 0) out[n] = NEDGE;   // sentinel (padded buffer)
}

// Level-2 scatter: one block per bucket; destination window is the ~32-64KB
// CSR slice for this bucket's 1024 nodes -> L2-resident, full-line writebacks.
__global__ __launch_bounds__(256) void scat2_k(
    const int* __restrict__ bCnt,
    const ull* __restrict__ bktU, const ull* __restrict__ bktV,
    int* __restrict__ posU, int* __restrict__ posV,
    ull* __restrict__ eU, ull* __restrict__ eV)
{
    int b = blockIdx.x;
    if (b < NBU) {
        int k = b / RU, baseR = (b % RU) << 10;
        int cnt = bCnt[b]; if (cnt > CAPU) cnt = CAPU;
        const ull* src = bktU + (size_t)b * CAPU;
        for (int i = threadIdx.x; i < cnt; i += 256) {
            ull en = src[i];
            uint w0 = (uint)en;
            int c = w0 & 0xFFFF;
            int r = baseR + (int)(w0 >> 16);
            int p = atomicAdd(&posU[k * NU + r], 1);
            __builtin_nontemporal_store((en & 0xFFFFFFFF00000000ull) |
                                        (uint)(c * (TMPW * 2)), &eU[p]);
        }
    } else {
        int bb = b - NBU;
        int k = bb / RV, baseC = (bb % RV) << 10;
        int cnt = bCnt[b]; if (cnt > CAPV) cnt = CAPV;
        const ull* src = bktV + (size_t)bb * CAPV;
        for (int i = threadIdx.x; i < cnt; i += 256) {
            ull en = src[i];
            uint w0 = (uint)en;
            int r = w0 & 0x1FFFF;
            int c = baseC + (int)(w0 >> 17);
            int p = atomicAdd(&posV[k * NV + c], 1);
            __builtin_nontemporal_store((en & 0xFFFFFFFF00000000ull) |
                                        (uint)(r * (TMPW * 2)), &eV[p]);
        }
    }
}

// ---------------------------------------------------------------------------
// Merged-support CSR aggregation: ONE wave per node, all supports [K0,K0+NK)
// in one interleaved latency chain (rowPtrs -> edges -> gathers -> fma).
template<int K0, int NK, int B, int NNODE>
__device__ __forceinline__ void agg_do(
    const int* __restrict__ rowPtr, const int2* __restrict__ eArr,
    const char* __restrict__ tSrc, int n, uint lane4,
    float* __restrict__ a0, float* __restrict__ a1)
{
    int s[NK], d[NK];
    #pragma unroll
    for (int kk = 0; kk < NK; ++kk) {
        int g = (K0 + kk) * NNODE + n;
        int ss = rowPtr[g];
        int ee = rowPtr[g + 1];     // sentinel covers the last segment
        s[kk] = ss; d[kk] = ee - ss;
    }
    int2 ed[NK][B]; uint gw[NK][B];
    #pragma unroll
    for (int kk = 0; kk < NK; ++kk)
        #pragma unroll
        for (int i = 0; i < B; ++i) {
            int idx = (i < d[kk]) ? i : 0;
            int2 t = eArr[s[kk] + idx];
            if (i >= d[kk]) t.x = 0;
            ed[kk][i] = t;
        }
    #pragma unroll
    for (int kk = 0; kk < NK; ++kk)
        #pragma unroll
        for (int i = 0; i < B; ++i)
            gw[kk][i] = *(const uint*)(tSrc + ((uint)ed[kk][i].x + lane4 + ((uint)(K0 + kk) << 8)));
    #pragma unroll
    for (int kk = 0; kk < NK; ++kk) {
        float x0 = 0.f, x1 = 0.f;
        #pragma unroll
        for (int i = 0; i < B; ++i)
            if (i < d[kk]) {
                float v = __int_as_float(ed[kk][i].y);
                x0 = fmaf(v, lof(gw[kk][i]), x0);
                x1 = fmaf(v, hif(gw[kk][i]), x1);
            }
        a0[K0 + kk] = x0; a1[K0 + kk] = x1;
    }
    #pragma unroll
    for (int kk = 0; kk < NK; ++kk) {
        if (d[kk] > B) {            // wave-uniform branch
            int2 e1[B]; uint g1[B];
            #pragma unroll
            for (int i = 0; i < B; ++i) {
                int idx = (B + i < d[kk]) ? B + i : B;
                int2 t = eArr[s[kk] + idx];
                if (B + i >= d[kk]) t.x = 0;
                e1[i] = t;
            }
            #pragma unroll
            for (int i = 0; i < B; ++i)
                g1[i] = *(const uint*)(tSrc + ((uint)e1[i].x + lane4 + ((uint)(K0 + kk) << 8)));
            #pragma unroll
            for (int i = 0; i < B; ++i)
                if (B + i < d[kk]) {
                    float v = __int_as_float(e1[i].y);
                    a0[K0 + kk] = fmaf(v, lof(g1[i]), a0[K0 + kk]);
                    a1[K0 + kk] = fmaf(v, hif(g1[i]), a1[K0 + kk]);
                }
            for (int p = 2 * B; p < d[kk]; ++p) {
                int2 t = eArr[s[kk] + p];
                uint g = *(const uint*)(tSrc + ((uint)t.x + lane4 + ((uint)(K0 + kk) << 8)));
                float v = __int_as_float(t.y);
                a0[K0 + kk] = fmaf(v, lof(g), a0[K0 + kk]);
                a1[K0 + kk] = fmaf(v, hif(g), a1[K0 + kk]);
            }
        }
    }
}

__global__ __launch_bounds__(256) void agg_csr_k(
    const int* __restrict__ rowPtrU, const int2* __restrict__ eU,
    const int* __restrict__ rowPtrV, const int2* __restrict__ eV,
    const ushort* __restrict__ tmpU, const ushort* __restrict__ tmpV,
    ushort* __restrict__ Xu, ushort* __restrict__ Xv)
{
    const int lane = threadIdx.x & 63;
    const int wv = blockIdx.x * 4 + (threadIdx.x >> 6);   // node id (U then V)
    const uint lane4 = (uint)(((lane < 50) ? lane : 49) << 2);

    float a0[KSUP], a1[KSUP];
    ushort* Xrow;
    if (wv < NU) {
        agg_do<0, KSUP, 4, NU>(rowPtrU, eU, (const char*)tmpV, wv, lane4, a0, a1);
        Xrow = Xu + (size_t)wv * XW;
    } else {
        int n = wv - NU;
        agg_do<0, 3, 8, NV>(rowPtrV, eV, (const char*)tmpU, n, lane4, a0, a1);
        agg_do<3, 2, 8, NV>(rowPtrV, eV, (const char*)tmpU, n, lane4, a0, a1);
        Xrow = Xv + (size_t)n * XW;
    }
    #pragma unroll
    for (int k = 0; k < KSUP; ++k) {
        uint payload = (uint)f2bf(fmaxf(a0[k], 0.f)) |
                       ((uint)f2bf(fmaxf(a1[k], 0.f)) << 16);
        if (lane < 50)
            __builtin_nontemporal_store(payload, (uint*)(Xrow + k * FSUP) + lane);
    }
    if (lane < 6)
        __builtin_nontemporal_store(0u, (uint*)(Xrow + 564) + lane);
}

// ---------------------------------------------------------------------------
// final decoder: basis[b] = dot(embU[u], Vb[v][b]); out = basis @ cls
__global__ __launch_bounds__(256) void dec_k(
    const int* __restrict__ ue, const int* __restrict__ ie,
    const ushort* __restrict__ embU, const ushort* __restrict__ Vb,
    const float* __restrict__ cls, float* __restrict__ out, int nE)
{
    int e = blockIdx.x * 8 + (threadIdx.x >> 5);
    if (e >= nE) return;
    int lane = threadIdx.x & 31;
    int u = ue[e], v = ie[e];
    const uint* pu = (const uint*)(embU + (size_t)u * DENC);        // 64 u32
    const uint* pv = (const uint*)(Vb + (size_t)v * (NBAS * DENC)); // 192 u32
    uint u0 = pu[lane], u1 = pu[lane + 32];
    uint b0[NBAS], b1[NBAS];
    #pragma unroll
    for (int b = 0; b < NBAS; ++b) {
        b0[b] = pv[b * 64 + lane];
        b1[b] = pv[b * 64 + 32 + lane];
    }
    float u0l = lof(u0), u0h = hif(u0), u1l = lof(u1), u1h = hif(u1);
    float s[NBAS];
    #pragma unroll
    for (int b = 0; b < NBAS; ++b) {
        float t = lof(b0[b]) * u0l;
        t = fmaf(hif(b0[b]), u0h, t);
        t = fmaf(lof(b1[b]), u1l, t);
        s[b] = fmaf(hif(b1[b]), u1h, t);
    }
    #pragma unroll
    for (int off = 16; off; off >>= 1)
        #pragma unroll
        for (int b = 0; b < NBAS; ++b) s[b] += __shfl_xor(s[b], off, 32);
    if (lane < NCLS) {
        float o = 0.f;
        #pragma unroll
        for (int b = 0; b < NBAS; ++b) o += s[b] * cls[b * NCLS + lane];
        out[(size_t)e * NCLS + lane] = o;
    }
}

// ---------------------------------------------------------------------------
extern "C" void kernel_launch(void* const* d_in, const int* in_sizes, int n_in,
                              void* d_out, int out_size, void* d_ws, size_t ws_size,
                              hipStream_t stream) {
    const int*   sup_u  = (const int*)  d_in[0];
    const int*   sup_i  = (const int*)  d_in[1];
    const float* sup_v  = (const float*)d_in[2];
    const float* u_in   = (const float*)d_in[3];
    const float* v_in   = (const float*)d_in[4];
    const float* u_side = (const float*)d_in[5];
    const float* v_side = (const float*)d_in[6];
    const int*   ue     = (const int*)  d_in[7];
    const int*   ie     = (const int*)  d_in[8];
    const float* W_enc  = (const float*)d_in[9];
    const float* Wu1    = (const float*)d_in[10];
    const float* bu1    = (const float*)d_in[11];
    const float* Wi1    = (const float*)d_in[12];
    const float* bi1    = (const float*)d_in[13];
    const float* Wu2    = (const float*)d_in[14];
    const float* Wi2    = (const float*)d_in[15];
    const float* dec_W  = (const float*)d_in[16];
    const float* deccls = (const float*)d_in[17];

    char* ws = (char*)d_ws;
    // timeline-overlaid workspace (max ~414M):
    // @0: u_bf [NU][512] (102.4M) -> Xu [NU][576] (115.2M)
    // @102.4M: v_bf [NV][512] (51.2M); Xv @115.2M [NV][576] (57.6M) ends 172.8M
    ushort* u_bf   = (ushort*)(ws);
    ushort* v_bf   = (ushort*)(ws + 102400000LL);
    ushort* Xu     = (ushort*)(ws);
    ushort* Xv     = (ushort*)(ws + 115200000LL);
    // CSR @176M (dead after agg); rowPtr regions padded for the +1 sentinel.
    int*    histU  = (int*)(ws + 176000000LL);          // [5][NU] 2M
    int*    histV  = (int*)(ws + 178000000LL);          // [5][NV] 1M
    int*    rowPtrU= (int*)(ws + 179000000LL);          // 2M + 4 sentinel
    int*    rowPtrV= (int*)(ws + 181200000LL);          // 1M + 4 sentinel
    int*    posU   = (int*)(ws + 182400000LL);          // 2M
    int*    posV   = (int*)(ws + 184600000LL);          // 1M
    int*    bsums  = (int*)(ws + 185800000LL);          // 4KB
    int*    bCnt   = (int*)(ws + 185810000LL);          // [735] contiguous
    ull*    eU     = (ull*)(ws + 186000000LL);          // [2M] 16M
    ull*    eV     = (ull*)(ws + 202000000LL);          // [2M] 16M ends 218M
    // tmp @220M (dead after agg): tmpU [NU][640] 128M, tmpV [NV][640] 64M
    ushort* tmpU   = (ushort*)(ws + 220000000LL);
    ushort* tmpV   = (ushort*)(ws + 348000000LL);       // ends 412M
    // L1 buckets: overlay on tmp region (dead before encoder GEMMs write tmp)
    ull*    bktU   = (ull*)(ws + 220000000LL);          // 490*5120*8  = 20.1M
    ull*    bktV   = (ull*)(ws + 241000000LL);          // 245*10240*8 = 20.1M ends 261.1M
    // post-agg overlays:
    ushort* embUbf = (ushort*)(ws + 176000000LL);       // [NU][128] 25.6M (over CSR)
    ushort* embVbf = (ushort*)(ws + 202000000LL);       // [NV][128] 12.8M (over eV)
    ushort* Vb     = (ushort*)(ws + 220000000LL);       // [NV][384] 38.4M (over tmp)
    // weights @412M:
    ushort* WencT2 = (ushort*)(ws + 412000000LL);       // [640][512] 0.66M
    ushort* W2ufT  = (ushort*)(ws + 413000000LL);       // [128][576] 0.15M
    ushort* W2ifT  = (ushort*)(ws + 413200000LL);       // [128][576] 0.15M
    ushort* decbf  = (ushort*)(ws + 413400000LL);       // [384][128] 0.10M

    dim3 blk(256);
    const int gu128 = (NU + 127) / 128;   // 782
    const int gv128 = (NV + 127) / 128;   // 391
    const int gu64  = (NU + 63) / 64;     // 1563
    const int gv64  = (NV + 63) / 64;     // 782
    const int gB    = (NEDGE + CHUNK - 1) / CHUNK;   // 245

    // ---- phase 1: bf16 conversions + CSR build (two-level scatter) ----
    cvt_in_k<<<dim3((NU + NV) * 512 / 4 / 256), blk, 0, stream>>>(u_in, v_in, u_bf, v_bf);
    cvt_wencT2_k<<<dim3(TMPW * 512 / 256), blk, 0, stream>>>(W_enc, WencT2);
    cvt_w2fT2_k<<<dim3((DENC * XW + 255) / 256, 2), blk, 0, stream>>>(Wu2, Wi2, W2ufT, W2ifT);
    cvt_k<<<dim3((NBAS * DENC * DENC / 4 + 255) / 256), blk, 0, stream>>>(
        dec_W, decbf, (long)NBAS * DENC * DENC);

    hipMemsetAsync(histU, 0, 3000000LL, stream);        // histU + histV
    hipMemsetAsync(bCnt, 0, 4096, stream);              // bucket counters
    binhist_k<<<dim3(gB), blk, 0, stream>>>(sup_u, sup_i, sup_v,
                                            histU, histV, bCnt, bktU, bktV);
    scan_reduce_k<<<dim3(245), blk, 0, stream>>>(histU, bsums, KSUP * NU);
    scan_bs_k<<<dim3(1), blk, 0, stream>>>(bsums, 245);
    scan_write_k<<<dim3(245), blk, 0, stream>>>(histU, bsums, rowPtrU, posU, KSUP * NU);
    scan_reduce_k<<<dim3(123), blk, 0, stream>>>(histV, bsums, KSUP * NV);
    scan_bs_k<<<dim3(1), blk, 0, stream>>>(bsums, 123);
    scan_write_k<<<dim3(123), blk, 0, stream>>>(histV, bsums, rowPtrV, posV, KSUP * NV);
    scat2_k<<<dim3(NBT), blk, 0, stream>>>(bCnt, bktU, bktV, posU, posV, eU, eV);

    // ---- phase 2: encoder GEMMs into padded tmp (N=640, 256B slices) ----
    gemm_bf16_k<1><<<dim3(gu128, TMPW / 128), blk, 0, stream>>>(
        u_bf, WencT2, tmpU, NU, TMPW, 512, TMPW);
    gemm_bf16_k<1><<<dim3(gv128, TMPW / 128), blk, 0, stream>>>(
        v_bf, WencT2, tmpV, NV, TMPW, 512, TMPW);

    // ---- phase 3: merged CSR aggregation (1 wave/node, 5 supports) ----
    agg_csr_k<<<dim3((NU + NV) / 4), blk, 0, stream>>>(
        rowPtrU, (const int2*)eU, rowPtrV, (const int2*)eV, tmpU, tmpV, Xu, Xv);

    // ---- phase 4: side dense -> X cols 500..563 (bf16) ----
    gemm_side_k<<<dim3(gu64), blk, 0, stream>>>(u_side, Wu1, bu1, Xu, NU, DSIDE);
    gemm_side_k<<<dim3(gv64), blk, 0, stream>>>(v_side, Wi1, bi1, Xv, NV, DSIDE);

    // ---- phase 5: dense2 = X @ W2fT (K=576) -> emb bf16 ----
    gemm_bf16_k<1><<<dim3(gu128, 1), blk, 0, stream>>>(Xu, W2ufT, embUbf, NU, 128, XW, 128);
    gemm_bf16_k<1><<<dim3(gv128, 1), blk, 0, stream>>>(Xv, W2ifT, embVbf, NV, 128, XW, 128);

    // ---- phase 6: decoder precompute on V side: Vb = embV @ decbf^T ----
    gemm_bf16_k<1><<<dim3(gv128, 3), blk, 0, stream>>>(embVbf, decbf, Vb, NV, 384, 128, 384);

    // ---- phase 7: final decoder over edges ----
    dec_k<<<dim3(NE / 8), blk, 0, stream>>>(ue, ie, embUbf, Vb, deccls, (float*)d_out, NE);
}